// Round 11
// baseline (278.827 us; speedup 1.0000x reference)
//
#include <hip/hip_runtime.h>
#include <math.h>
#include <stdint.h>

// PedestrianDetector v16: barrier-free drifting-wave streams + LDS-resident W.
//
// Evidence: probe reads this buffer at 6.3 TB/s; every scalar-W variant sits
// at 3.35 TB/s regardless of instruction (v15), address map (v14), granule
// (v13), depth (v6), rotation (v7), NT (v11). The scalar-W trick forces
// 64-row column-lockstep (density-1/8 walk, barrier-phased). v16 drops it:
//  - wave g owns 4 ADJACENT rows [4g, 4g+4); streams them in 1KB ascending
//    steps (global_load_dwordx4, probe-class addresses), NO barriers in the
//    stream, waves drift freely.
//  - per-wave window stagger ((it+g)&7) covers all 8 column offsets
//    machine-wide at every instant (engineered density, no lockstep).
//  - W transposed in LDS once (Wt[15][2048], 122,880B dynamic; staging path
//    proven in v13/v14/v15). Read as stride-16B ds_read_b128 (conflict-free),
//    shared across the wave's 4 rows -> LDS traffic 3.75x features
//    (= ~37 B/cy at 10 B/cy feature rate, under the 85 B/cy b128 ceiling).
//  - acc[4][15] in VGPR; ONE cross-lane shfl-xor reduce per wave at the end;
//    lanes 0..3 run the (verbatim) sigmoid/top-3/pack epilogue for their row.
// 256 blocks x 1024 threads (16 waves), 1 block/CU (LDS-bound), 16 waves/CU.

#define DCOLS 2048
#define WROWS 4                // rows per wave
#define ITW   256              // d per iteration (1KB per row)
#define NIT   (DCOLS / ITW)    // 8 iterations
#define WLDSF (15 * DCOLS)     // 30720 floats = 122,880 B
#define LDSB  (WLDSF * 4)

__global__ __launch_bounds__(1024, 4)
void ped_det_kernel(const float* __restrict__ feat,
                    const float* __restrict__ Wb,   // [2048][12]
                    const float* __restrict__ bb,   // [12]
                    const float* __restrict__ Wc,   // [2048][3]
                    const float* __restrict__ bc,   // [3]
                    float* __restrict__ out,
                    int nrows)
{
    extern __shared__ __align__(16) float Wt[];   // [15][2048] transposed weights

    const int t = threadIdx.x;

    // ---- stage W transposed: Wt[j][d]. One-time; W is L2-resident after the
    // first blocks (122KB total, all blocks read the same data).
#pragma unroll
    for (int e0 = 0; e0 < WLDSF; e0 += 1024) {
        const int e = e0 + t;
        const int j = e >> 11;          // e / 2048
        const int d = e & 2047;
        Wt[e] = (j < 12) ? Wb[(size_t)d * 12 + j] : Wc[(size_t)d * 3 + (j - 12)];
    }
    __syncthreads();   // the ONLY barrier before the epilogue

    const int lane = t & 63;
    const int wu   = t >> 6;
    const int g    = blockIdx.x * 16 + wu;      // global wave id, 4096 waves
    const int rowBase = g * WROWS;              // 4 adjacent rows

    const float* fp = feat + (size_t)rowBase * DCOLS;

    float acc[WROWS][15];
#pragma unroll
    for (int q = 0; q < WROWS; ++q)
#pragma unroll
        for (int j = 0; j < 15; ++j) acc[q][j] = 0.0f;

    // ---- barrier-free stream: 8 staggered 1KB windows per row
    for (int it = 0; it < NIT; ++it) {
        const int win   = (it + g) & (NIT - 1);        // per-wave phase stagger
        const int dbase = win * ITW + (lane << 2);     // lane's 4-d slice

        const float4 f0 = *(const float4*)(fp + 0 * DCOLS + dbase);
        const float4 f1 = *(const float4*)(fp + 1 * DCOLS + dbase);
        const float4 f2 = *(const float4*)(fp + 2 * DCOLS + dbase);
        const float4 f3 = *(const float4*)(fp + 3 * DCOLS + dbase);

#pragma unroll
        for (int j = 0; j < 15; ++j) {
            // stride-16B ascending b128: conflict-free, shared by 4 rows
            const float4 wv = *(const float4*)(&Wt[j * DCOLS + dbase]);
            acc[0][j] += f0.x * wv.x + f0.y * wv.y + f0.z * wv.z + f0.w * wv.w;
            acc[1][j] += f1.x * wv.x + f1.y * wv.y + f1.z * wv.z + f1.w * wv.w;
            acc[2][j] += f2.x * wv.x + f2.y * wv.y + f2.z * wv.z + f2.w * wv.w;
            acc[3][j] += f3.x * wv.x + f3.y * wv.y + f3.z * wv.z + f3.w * wv.w;
        }
    }

    // ---- cross-lane reduce (sum over the 64 disjoint d-slices)
#pragma unroll
    for (int q = 0; q < WROWS; ++q)
#pragma unroll
        for (int j = 0; j < 15; ++j) {
            float v = acc[q][j];
            v += __shfl_xor(v, 1);
            v += __shfl_xor(v, 2);
            v += __shfl_xor(v, 4);
            v += __shfl_xor(v, 8);
            v += __shfl_xor(v, 16);
            v += __shfl_xor(v, 32);
            acc[q][j] = v;
        }

    // ---- epilogue: lane q (<4) handles row rowBase+q (logic verbatim v4..v15)
    if (lane < WROWS) {
        float s[15];
#pragma unroll
        for (int j = 0; j < 15; ++j) {
            const float v = (lane == 0) ? acc[0][j]
                          : (lane == 1) ? acc[1][j]
                          : (lane == 2) ? acc[2][j]
                          :               acc[3][j];          // static idx (rule 20)
            s[j] = v + ((j < 12) ? bb[j] : bc[j - 12]);
        }

        float conf[3];
#pragma unroll
        for (int a = 0; a < 3; ++a)
            conf[a] = 1.0f / (1.0f + __expf(-s[12 + a]));

        int i0 = 0; float m0 = conf[0];
        if (conf[1] > m0) { i0 = 1; m0 = conf[1]; }
        if (conf[2] > m0) { i0 = 2; m0 = conf[2]; }
        const int ra = (i0 == 0) ? 1 : 0;
        const int rb = (i0 == 2) ? 1 : 2;
        int i1, i2;
        if (conf[rb] > conf[ra]) { i1 = rb; i2 = ra; }
        else                     { i1 = ra; i2 = rb; }
        const int idx[3] = { i0, i1, i2 };

        const int ro = rowBase + lane;
        float* boxout  = out + (size_t)ro * 12;
        float* confout = out + (size_t)nrows * 12 + (size_t)ro * 3;
        float* valout  = out + (size_t)nrows * 15 + (size_t)ro * 3;
#pragma unroll
        for (int sl = 0; sl < 3; ++sl) {
            const int   a   = idx[sl];
            const float cv  = conf[a];
            const bool  vld = cv > 0.5f;
            const float b0 = (a == 0) ? s[0] : (a == 1) ? s[4]  : s[8];
            const float b1 = (a == 0) ? s[1] : (a == 1) ? s[5]  : s[9];
            const float b2 = (a == 0) ? s[2] : (a == 1) ? s[6]  : s[10];
            const float b3 = (a == 0) ? s[3] : (a == 1) ? s[7]  : s[11];
            float4 bx;
            bx.x = vld ? b0 : 0.0f;
            bx.y = vld ? b1 : 0.0f;
            bx.z = vld ? b2 : 0.0f;
            bx.w = vld ? b3 : 0.0f;
            *(float4*)(boxout + sl * 4) = bx;
            confout[sl] = cv;
            valout[sl]  = vld ? 1.0f : 0.0f;
        }
    }
}

extern "C" void kernel_launch(void* const* d_in, const int* in_sizes, int n_in,
                              void* d_out, int out_size, void* d_ws, size_t ws_size,
                              hipStream_t stream) {
    const float* feat = (const float*)d_in[0];
    const float* Wb   = (const float*)d_in[1];
    const float* bb   = (const float*)d_in[2];
    const float* Wc   = (const float*)d_in[3];
    const float* bc   = (const float*)d_in[4];
    float* out = (float*)d_out;

    const int nrows   = in_sizes[0] / DCOLS;    // 16384
    const int nblocks = nrows / (16 * WROWS);   // 256 -> 1 block/CU

    static int dyn_ok = -1;   // one-time attribute setup (host-side, capture-safe)
    if (dyn_ok < 0) {
        hipError_t e = hipFuncSetAttribute(
            (const void*)ped_det_kernel,
            hipFuncAttributeMaxDynamicSharedMemorySize, LDSB);
        dyn_ok = (e == hipSuccess) ? 1 : 0;
    }

    ped_det_kernel<<<dim3(nblocks), dim3(1024), LDSB, stream>>>(
        feat, Wb, bb, Wc, bc, out, nrows);
}

// Round 12
// 249.271 us; speedup vs baseline: 1.1186x; 1.1186x over previous
//
#include <hip/hip_runtime.h>
#include <math.h>
#include <stdint.h>

// PedestrianDetector v17 = v16 with ONE variable changed: __launch_bounds__
// second arg 4 -> 1. v16's VGPR allocator was capped at 64 (8 waves/SIMD
// target) while the kernel's working set (acc[4][15] + 4 staged float4 + wv)
// needs ~110 -> everything spilled to scratch (counters: VGPR=64, FETCH 419MB,
// WRITE 750MB = 3x traffic, 279us). (1024,1) caps at 1 block/CU = 4 waves/
// SIMD = 128 VGPRs: demand fits, no spill, occupancy unchanged (16 waves/CU,
// LDS-bound at 120KB anyway).
//
// Structure (v16, unchanged): barrier-free drifting-wave streams + LDS-resident
// transposed W. Wave g owns 4 adjacent rows; streams 8 staggered 1KB windows
// (probe-class ascending float4 loads, no barriers); W read as conflict-free
// stride-16B ds_read_b128 shared across 4 rows (amplification 3.75x);
// per-wave shfl-xor reduce; lanes 0..3 run the verbatim epilogue.

#define DCOLS 2048
#define WROWS 4                // rows per wave
#define ITW   256              // d per iteration (1KB per row)
#define NIT   (DCOLS / ITW)    // 8 iterations
#define WLDSF (15 * DCOLS)     // 30720 floats = 122,880 B
#define LDSB  (WLDSF * 4)

__global__ __launch_bounds__(1024, 1)
void ped_det_kernel(const float* __restrict__ feat,
                    const float* __restrict__ Wb,   // [2048][12]
                    const float* __restrict__ bb,   // [12]
                    const float* __restrict__ Wc,   // [2048][3]
                    const float* __restrict__ bc,   // [3]
                    float* __restrict__ out,
                    int nrows)
{
    extern __shared__ __align__(16) float Wt[];   // [15][2048] transposed weights

    const int t = threadIdx.x;

    // ---- stage W transposed: Wt[j][d]. One-time; W totals 122KB, L2-resident.
#pragma unroll
    for (int e0 = 0; e0 < WLDSF; e0 += 1024) {
        const int e = e0 + t;
        const int j = e >> 11;          // e / 2048
        const int d = e & 2047;
        Wt[e] = (j < 12) ? Wb[(size_t)d * 12 + j] : Wc[(size_t)d * 3 + (j - 12)];
    }
    __syncthreads();   // the ONLY barrier before the epilogue

    const int lane = t & 63;
    const int wu   = t >> 6;
    const int g    = blockIdx.x * 16 + wu;      // global wave id, 4096 waves
    const int rowBase = g * WROWS;              // 4 adjacent rows

    const float* fp = feat + (size_t)rowBase * DCOLS;

    float acc[WROWS][15];
#pragma unroll
    for (int q = 0; q < WROWS; ++q)
#pragma unroll
        for (int j = 0; j < 15; ++j) acc[q][j] = 0.0f;

    // ---- barrier-free stream: 8 staggered 1KB windows per row
    for (int it = 0; it < NIT; ++it) {
        const int win   = (it + g) & (NIT - 1);        // per-wave phase stagger
        const int dbase = win * ITW + (lane << 2);     // lane's 4-d slice

        const float4 f0 = *(const float4*)(fp + 0 * DCOLS + dbase);
        const float4 f1 = *(const float4*)(fp + 1 * DCOLS + dbase);
        const float4 f2 = *(const float4*)(fp + 2 * DCOLS + dbase);
        const float4 f3 = *(const float4*)(fp + 3 * DCOLS + dbase);

#pragma unroll
        for (int j = 0; j < 15; ++j) {
            // stride-16B ascending b128: 2-way bank aliasing = free (m136),
            // shared by the wave's 4 rows
            const float4 wv = *(const float4*)(&Wt[j * DCOLS + dbase]);
            acc[0][j] += f0.x * wv.x + f0.y * wv.y + f0.z * wv.z + f0.w * wv.w;
            acc[1][j] += f1.x * wv.x + f1.y * wv.y + f1.z * wv.z + f1.w * wv.w;
            acc[2][j] += f2.x * wv.x + f2.y * wv.y + f2.z * wv.z + f2.w * wv.w;
            acc[3][j] += f3.x * wv.x + f3.y * wv.y + f3.z * wv.z + f3.w * wv.w;
        }
    }

    // ---- cross-lane reduce (sum over the 64 disjoint d-slices)
#pragma unroll
    for (int q = 0; q < WROWS; ++q)
#pragma unroll
        for (int j = 0; j < 15; ++j) {
            float v = acc[q][j];
            v += __shfl_xor(v, 1);
            v += __shfl_xor(v, 2);
            v += __shfl_xor(v, 4);
            v += __shfl_xor(v, 8);
            v += __shfl_xor(v, 16);
            v += __shfl_xor(v, 32);
            acc[q][j] = v;
        }

    // ---- epilogue: lane q (<4) handles row rowBase+q (logic verbatim v4..v15)
    if (lane < WROWS) {
        float s[15];
#pragma unroll
        for (int j = 0; j < 15; ++j) {
            const float v = (lane == 0) ? acc[0][j]
                          : (lane == 1) ? acc[1][j]
                          : (lane == 2) ? acc[2][j]
                          :               acc[3][j];          // static idx (rule 20)
            s[j] = v + ((j < 12) ? bb[j] : bc[j - 12]);
        }

        float conf[3];
#pragma unroll
        for (int a = 0; a < 3; ++a)
            conf[a] = 1.0f / (1.0f + __expf(-s[12 + a]));

        int i0 = 0; float m0 = conf[0];
        if (conf[1] > m0) { i0 = 1; m0 = conf[1]; }
        if (conf[2] > m0) { i0 = 2; m0 = conf[2]; }
        const int ra = (i0 == 0) ? 1 : 0;
        const int rb = (i0 == 2) ? 1 : 2;
        int i1, i2;
        if (conf[rb] > conf[ra]) { i1 = rb; i2 = ra; }
        else                     { i1 = ra; i2 = rb; }
        const int idx[3] = { i0, i1, i2 };

        const int ro = rowBase + lane;
        float* boxout  = out + (size_t)ro * 12;
        float* confout = out + (size_t)nrows * 12 + (size_t)ro * 3;
        float* valout  = out + (size_t)nrows * 15 + (size_t)ro * 3;
#pragma unroll
        for (int sl = 0; sl < 3; ++sl) {
            const int   a   = idx[sl];
            const float cv  = conf[a];
            const bool  vld = cv > 0.5f;
            const float b0 = (a == 0) ? s[0] : (a == 1) ? s[4]  : s[8];
            const float b1 = (a == 0) ? s[1] : (a == 1) ? s[5]  : s[9];
            const float b2 = (a == 0) ? s[2] : (a == 1) ? s[6]  : s[10];
            const float b3 = (a == 0) ? s[3] : (a == 1) ? s[7]  : s[11];
            float4 bx;
            bx.x = vld ? b0 : 0.0f;
            bx.y = vld ? b1 : 0.0f;
            bx.z = vld ? b2 : 0.0f;
            bx.w = vld ? b3 : 0.0f;
            *(float4*)(boxout + sl * 4) = bx;
            confout[sl] = cv;
            valout[sl]  = vld ? 1.0f : 0.0f;
        }
    }
}

extern "C" void kernel_launch(void* const* d_in, const int* in_sizes, int n_in,
                              void* d_out, int out_size, void* d_ws, size_t ws_size,
                              hipStream_t stream) {
    const float* feat = (const float*)d_in[0];
    const float* Wb   = (const float*)d_in[1];
    const float* bb   = (const float*)d_in[2];
    const float* Wc   = (const float*)d_in[3];
    const float* bc   = (const float*)d_in[4];
    float* out = (float*)d_out;

    const int nrows   = in_sizes[0] / DCOLS;    // 16384
    const int nblocks = nrows / (16 * WROWS);   // 256 -> 1 block/CU

    static int dyn_ok = -1;   // one-time attribute setup (host-side, capture-safe)
    if (dyn_ok < 0) {
        hipError_t e = hipFuncSetAttribute(
            (const void*)ped_det_kernel,
            hipFuncAttributeMaxDynamicSharedMemorySize, LDSB);
        dyn_ok = (e == hipSuccess) ? 1 : 0;
    }

    ped_det_kernel<<<dim3(nblocks), dim3(1024), LDSB, stream>>>(
        feat, Wb, bb, Wc, bc, out, nrows);
}